// Round 6
// baseline (887.950 us; speedup 1.0000x reference)
//
#include <hip/hip_runtime.h>

// DCN v2 (modulated deformable 3x3 conv) + BN(eval) + ReLU, fully fused.
// B=4, C=64, O=64, H=W=128, K=9. fp32 in/out (reference dtypes), fp32 math.
//
// Block = 64 pixels (lane = pixel), 4 waves split input channels 16-each.
// Grid 1024 blocks. __launch_bounds__(256,3): 170-VGPR budget -- round 5's
// (256,4) forced a 64-VGPR allocation that spilled acc[64] to scratch
// (WRITE_SIZE 129MB vs 16.4MB of output; FETCH 964MB). Round 4 proved this
// live set fits in 108 VGPRs, which gives 4 waves/EU naturally.
//
// Layouts:
//   x     [4][64][128][128]
//   w_off [27][64][3][3]   oc*576 + c*9 + t   (lane-invariant -> scalar loads)
//   wgt   [64][64][3][3]   o*576 + c*9 + t
//   offset channels: tap k -> y-off ch 2k, x-off ch 2k+1, mask ch 18+k

#define HH 128
#define WW 128

// LDS (floats):
//   [0..6911]    redA[4][27][64] (phase-A partials) / red[4][64][17] (phase-D, aliased)
//   [6912..8639] offs[27][64]
//   [8640..8767] sbuf[128] (BN scale | folded bias)
__global__ __launch_bounds__(256, 3) void DeformConv_14568529068723_kernel(
    const float* __restrict__ x,
    const float* __restrict__ w_off,
    const float* __restrict__ b_off,
    const float* __restrict__ wgt,
    const float* __restrict__ bias,
    const float* __restrict__ gamma,
    const float* __restrict__ beta,
    const float* __restrict__ rmean,
    const float* __restrict__ rvar,
    float* __restrict__ out)
{
    __shared__ float lds[8768];
    float* redA = lds;          // 4*27*64
    float* offs = lds + 6912;   // 27*64
    float* sbuf = lds + 8640;   // 128

    const int tid  = threadIdx.x;
    const int lane = tid & 63;
    const int wv   = tid >> 6;

    if (tid < 64) {
        float sc = gamma[tid] * __frsqrt_rn(rvar[tid] + 1e-5f);
        float b2 = (bias[tid] - rmean[tid]) * sc + beta[tid];
        sbuf[tid] = sc;
        sbuf[64 + tid] = b2;
    }

    const int p0   = blockIdx.x * 64;   // 64 consecutive pixels, same row
    const int b    = p0 >> 14;
    const int rem0 = p0 & 16383;
    const int h    = rem0 >> 7;
    const int w    = (rem0 & 127) + lane;
    const float* xb = x + ((size_t)b << 20);   // b * 64 * 16384
    const int c0 = wv * 16;

    // ---- Phase A: offset conv, wave wv handles channels [c0, c0+16) ----
    float acc27[27];
#pragma unroll
    for (int oc = 0; oc < 27; ++oc) acc27[oc] = 0.0f;

    for (int c = c0; c < c0 + 16; ++c) {
        float xv[9];
#pragma unroll
        for (int t = 0; t < 9; ++t) {
            int yy = h + t / 3 - 1;
            int xx = w + t % 3 - 1;
            bool ok = (yy >= 0) & (yy < HH) & (xx >= 0) & (xx < WW);
            int yc = min(max(yy, 0), HH - 1);
            int xc = min(max(xx, 0), WW - 1);
            float v = xb[(c << 14) + yc * WW + xc];
            xv[t] = ok ? v : 0.0f;
        }
#pragma unroll
        for (int oc = 0; oc < 27; ++oc) {
            const float* wr = w_off + oc * 576 + c * 9;   // lane-invariant
            float a = acc27[oc];
#pragma unroll
            for (int t = 0; t < 9; ++t)
                a = fmaf(xv[t], wr[t], a);
            acc27[oc] = a;
        }
    }
#pragma unroll
    for (int oc = 0; oc < 27; ++oc)
        redA[(wv * 27 + oc) * 64 + lane] = acc27[oc];
    __syncthreads();

    // reduce 4 partials + bias, sigmoid masks -> offs[27][64]
    for (int i = tid; i < 27 * 64; i += 256) {
        int oc = i >> 6;
        float v = redA[i] + redA[1728 + i] + redA[3456 + i] + redA[5184 + i] + b_off[oc];
        if (oc >= 18) v = 1.0f / (1.0f + __expf(-v));
        offs[i] = v;
    }
    __syncthreads();

    // ---- Phase B: bilinear setup (per-lane; corner validity folded into weights) ----
    int   ofs4[9][4];
    float cw[9][4];
#pragma unroll
    for (int k = 0; k < 9; ++k) {
        float o1 = offs[(2 * k) * 64 + lane];
        float o2 = offs[(2 * k + 1) * 64 + lane];
        float m  = offs[(18 + k) * 64 + lane];      // already sigmoided
        float py = (float)(h + k / 3 - 1) + o1;
        float px = (float)(w + k % 3 - 1) + o2;
        float y0f = floorf(py), x0f = floorf(px);
        float dy = py - y0f, dx = px - x0f;
        int y0 = (int)y0f, x0 = (int)x0f;
        int y1 = y0 + 1, x1 = x0 + 1;
        int yc0 = min(max(y0, 0), HH - 1), yc1 = min(max(y1, 0), HH - 1);
        int xc0 = min(max(x0, 0), WW - 1), xc1 = min(max(x1, 0), WW - 1);
        float vy0 = (y0 >= 0 && y0 < HH) ? 1.0f : 0.0f;
        float vy1 = (y1 >= 0 && y1 < HH) ? 1.0f : 0.0f;
        float vx0 = (x0 >= 0 && x0 < WW) ? 1.0f : 0.0f;
        float vx1 = (x1 >= 0 && x1 < WW) ? 1.0f : 0.0f;
        ofs4[k][0] = yc0 * WW + xc0;
        ofs4[k][1] = yc0 * WW + xc1;
        ofs4[k][2] = yc1 * WW + xc0;
        ofs4[k][3] = yc1 * WW + xc1;
        cw[k][0] = (1.0f - dy) * (1.0f - dx) * m * vy0 * vx0;
        cw[k][1] = (1.0f - dy) * dx * m * vy0 * vx1;
        cw[k][2] = dy * (1.0f - dx) * m * vy1 * vx0;
        cw[k][3] = dy * dx * m * vy1 * vx1;
    }

    // ---- Phase C: sampling + matvec over this wave's 16 channels ----
    float acc[64];
#pragma unroll
    for (int o = 0; o < 64; ++o) acc[o] = 0.0f;

    for (int c = c0; c < c0 + 16; ++c) {
        const float* xc = xb + (c << 14);
        float s[9];
#pragma unroll
        for (int k = 0; k < 9; ++k) {
            s[k] = cw[k][0] * xc[ofs4[k][0]]
                 + cw[k][1] * xc[ofs4[k][1]]
                 + cw[k][2] * xc[ofs4[k][2]]
                 + cw[k][3] * xc[ofs4[k][3]];
        }
#pragma unroll
        for (int o = 0; o < 64; ++o) {
            const float* wr = wgt + o * 576 + c * 9;   // lane-invariant
            float a = acc[o];
#pragma unroll
            for (int k = 0; k < 9; ++k)
                a = fmaf(s[k], wr[k], a);
            acc[o] = a;
        }
    }

    // ---- Phase D: cross-wave reduce (4 chunks of 16 outputs) + BN + ReLU ----
    float* red = lds;   // [4][64][17], aliases redA (done with it)
#pragma unroll
    for (int chunk = 0; chunk < 4; ++chunk) {
        __syncthreads();
#pragma unroll
        for (int j = 0; j < 16; ++j)
            red[(wv * 64 + lane) * 17 + j] = acc[chunk * 16 + j];
        __syncthreads();
#pragma unroll
        for (int q = 0; q < 4; ++q) {
            int oo = wv + q * 4;               // wave-uniform
            int o  = chunk * 16 + oo;
            float v = red[(0 * 64 + lane) * 17 + oo]
                    + red[(1 * 64 + lane) * 17 + oo]
                    + red[(2 * 64 + lane) * 17 + oo]
                    + red[(3 * 64 + lane) * 17 + oo];
            v = fmaxf(fmaf(v, sbuf[o], sbuf[64 + o]), 0.0f);
            out[(((size_t)(b * 64 + o)) << 14) + rem0 + lane] = v;
        }
    }
}

extern "C" void kernel_launch(void* const* d_in, const int* in_sizes, int n_in,
                              void* d_out, int out_size, void* d_ws, size_t ws_size,
                              hipStream_t stream) {
    (void)in_sizes; (void)n_in; (void)d_ws; (void)ws_size; (void)out_size;
    const float* x     = (const float*)d_in[0];
    const float* w_off = (const float*)d_in[1];
    const float* b_off = (const float*)d_in[2];
    const float* wgt   = (const float*)d_in[3];
    const float* bias  = (const float*)d_in[4];
    const float* gamma = (const float*)d_in[5];
    const float* beta  = (const float*)d_in[6];
    const float* rmean = (const float*)d_in[7];
    const float* rvar  = (const float*)d_in[8];
    float* outp = (float*)d_out;

    // 4*128*128 pixels / 64 per block = 1024 blocks
    DeformConv_14568529068723_kernel<<<dim3(1024), dim3(256), 0, stream>>>(
        x, w_off, b_off, wgt, bias, gamma, beta, rmean, rvar, outp);
}

// Round 7
// 625.727 us; speedup vs baseline: 1.4191x; 1.4191x over previous
//
#include <hip/hip_runtime.h>

// DCN v2 (modulated deformable 3x3 conv) + BN(eval) + ReLU, fully fused.
// B=4, C=64, O=64, H=W=128, K=9. fp32 in/out, fp32 math.
//
// Block = 64 pixels (lane = pixel), 4 waves split input channels 16-each,
// grid 1024 blocks (4 blocks/CU).
//
// REGISTER-ALLOC NOTE (rounds 4-6 evidence): plain __launch_bounds__(256)
// -> 108 VGPR, zero spill (WRITE_SIZE == output exactly). Any min-waves arg
// ((256,4) -> 64 VGPR, (256,3) -> 84 VGPR) forces massive scratch spill
// (+72..112 MB writes, +430..900 MB reads) AND scratch caps occupancy.
// Do not add a second launch_bounds argument here.
//
// Layouts:
//   x     [4][64][128][128]
//   w_off [27][64][3][3]   oc*576 + c*9 + t   (lane-invariant -> scalar loads)
//   wgt   [64][64][3][3]   o*576 + c*9 + t
//   offset channels: tap k -> y-off ch 2k, x-off ch 2k+1, mask ch 18+k

#define HH 128
#define WW 128

// LDS (floats):
//   [0..6911]    redA[4][27][64] (phase-A partials) / red[4][64][17] (phase-D, aliased)
//   [6912..8639] offs[27][64]
//   [8640..8767] sbuf[128] (BN scale | folded bias)
__global__ __launch_bounds__(256) void DeformConv_14568529068723_kernel(
    const float* __restrict__ x,
    const float* __restrict__ w_off,
    const float* __restrict__ b_off,
    const float* __restrict__ wgt,
    const float* __restrict__ bias,
    const float* __restrict__ gamma,
    const float* __restrict__ beta,
    const float* __restrict__ rmean,
    const float* __restrict__ rvar,
    float* __restrict__ out)
{
    __shared__ float lds[8768];
    float* redA = lds;          // 4*27*64
    float* offs = lds + 6912;   // 27*64
    float* sbuf = lds + 8640;   // 128

    const int tid  = threadIdx.x;
    const int lane = tid & 63;
    const int wv   = tid >> 6;

    if (tid < 64) {
        float sc = gamma[tid] * __frsqrt_rn(rvar[tid] + 1e-5f);
        float b2 = (bias[tid] - rmean[tid]) * sc + beta[tid];
        sbuf[tid] = sc;
        sbuf[64 + tid] = b2;
    }

    const int p0   = blockIdx.x * 64;   // 64 consecutive pixels, same row
    const int b    = p0 >> 14;
    const int rem0 = p0 & 16383;
    const int h    = rem0 >> 7;
    const int w    = (rem0 & 127) + lane;
    const float* xb = x + ((size_t)b << 20);   // b * 64 * 16384
    const int c0 = wv * 16;

    // ---- Phase A: offset conv, wave wv handles channels [c0, c0+16) ----
    {
        float acc27[27];
#pragma unroll
        for (int oc = 0; oc < 27; ++oc) acc27[oc] = 0.0f;

        for (int c = c0; c < c0 + 16; ++c) {
            float xv[9];
#pragma unroll
            for (int t = 0; t < 9; ++t) {
                int yy = h + t / 3 - 1;
                int xx = w + t % 3 - 1;
                bool ok = (yy >= 0) & (yy < HH) & (xx >= 0) & (xx < WW);
                int yc = min(max(yy, 0), HH - 1);
                int xc = min(max(xx, 0), WW - 1);
                float v = xb[(c << 14) + yc * WW + xc];
                xv[t] = ok ? v : 0.0f;
            }
#pragma unroll
            for (int oc = 0; oc < 27; ++oc) {
                const float* wr = w_off + oc * 576 + c * 9;   // lane-invariant
                float a = acc27[oc];
#pragma unroll
                for (int t = 0; t < 9; ++t)
                    a = fmaf(xv[t], wr[t], a);
                acc27[oc] = a;
            }
        }
#pragma unroll
        for (int oc = 0; oc < 27; ++oc)
            redA[(wv * 27 + oc) * 64 + lane] = acc27[oc];
    }
    __syncthreads();

    // reduce 4 partials + bias, sigmoid masks -> offs[27][64]
    for (int i = tid; i < 27 * 64; i += 256) {
        int oc = i >> 6;
        float v = redA[i] + redA[1728 + i] + redA[3456 + i] + redA[5184 + i] + b_off[oc];
        if (oc >= 18) v = 1.0f / (1.0f + __expf(-v));
        offs[i] = v;
    }
    __syncthreads();

    // ---- Phase B: bilinear setup (per-lane; corner validity folded into weights) ----
    int   ofs4[9][4];
    float cw[9][4];
#pragma unroll
    for (int k = 0; k < 9; ++k) {
        float o1 = offs[(2 * k) * 64 + lane];
        float o2 = offs[(2 * k + 1) * 64 + lane];
        float m  = offs[(18 + k) * 64 + lane];      // already sigmoided
        float py = (float)(h + k / 3 - 1) + o1;
        float px = (float)(w + k % 3 - 1) + o2;
        float y0f = floorf(py), x0f = floorf(px);
        float dy = py - y0f, dx = px - x0f;
        int y0 = (int)y0f, x0 = (int)x0f;
        int y1 = y0 + 1, x1 = x0 + 1;
        int yc0 = min(max(y0, 0), HH - 1), yc1 = min(max(y1, 0), HH - 1);
        int xc0 = min(max(x0, 0), WW - 1), xc1 = min(max(x1, 0), WW - 1);
        float vy0 = (y0 >= 0 && y0 < HH) ? 1.0f : 0.0f;
        float vy1 = (y1 >= 0 && y1 < HH) ? 1.0f : 0.0f;
        float vx0 = (x0 >= 0 && x0 < WW) ? 1.0f : 0.0f;
        float vx1 = (x1 >= 0 && x1 < WW) ? 1.0f : 0.0f;
        ofs4[k][0] = yc0 * WW + xc0;
        ofs4[k][1] = yc0 * WW + xc1;
        ofs4[k][2] = yc1 * WW + xc0;
        ofs4[k][3] = yc1 * WW + xc1;
        cw[k][0] = (1.0f - dy) * (1.0f - dx) * m * vy0 * vx0;
        cw[k][1] = (1.0f - dy) * dx * m * vy0 * vx1;
        cw[k][2] = dy * (1.0f - dx) * m * vy1 * vx0;
        cw[k][3] = dy * dx * m * vy1 * vx1;
    }

    // ---- Phase C: sampling + matvec over this wave's 16 channels ----
    float acc[64];
#pragma unroll
    for (int o = 0; o < 64; ++o) acc[o] = 0.0f;

    for (int c = c0; c < c0 + 16; ++c) {
        const float* xc = xb + (c << 14);
        float s[9];
#pragma unroll
        for (int k = 0; k < 9; ++k) {
            s[k] = cw[k][0] * xc[ofs4[k][0]]
                 + cw[k][1] * xc[ofs4[k][1]]
                 + cw[k][2] * xc[ofs4[k][2]]
                 + cw[k][3] * xc[ofs4[k][3]];
        }
#pragma unroll
        for (int o = 0; o < 64; ++o) {
            const float* wr = wgt + o * 576 + c * 9;   // lane-invariant
            float a = acc[o];
#pragma unroll
            for (int k = 0; k < 9; ++k)
                a = fmaf(s[k], wr[k], a);
            acc[o] = a;
        }
    }

    // ---- Phase D: cross-wave reduce (4 chunks of 16 outputs) + BN + ReLU ----
    float* red = lds;   // [4][64][17], aliases redA (done with it)
#pragma unroll
    for (int chunk = 0; chunk < 4; ++chunk) {
        __syncthreads();
#pragma unroll
        for (int j = 0; j < 16; ++j)
            red[(wv * 64 + lane) * 17 + j] = acc[chunk * 16 + j];
        __syncthreads();
#pragma unroll
        for (int q = 0; q < 4; ++q) {
            int oo = wv + q * 4;               // wave-uniform
            int o  = chunk * 16 + oo;
            float v = red[(0 * 64 + lane) * 17 + oo]
                    + red[(1 * 64 + lane) * 17 + oo]
                    + red[(2 * 64 + lane) * 17 + oo]
                    + red[(3 * 64 + lane) * 17 + oo];
            v = fmaxf(fmaf(v, sbuf[o], sbuf[64 + o]), 0.0f);
            out[(((size_t)(b * 64 + o)) << 14) + rem0 + lane] = v;
        }
    }
}

extern "C" void kernel_launch(void* const* d_in, const int* in_sizes, int n_in,
                              void* d_out, int out_size, void* d_ws, size_t ws_size,
                              hipStream_t stream) {
    (void)in_sizes; (void)n_in; (void)d_ws; (void)ws_size; (void)out_size;
    const float* x     = (const float*)d_in[0];
    const float* w_off = (const float*)d_in[1];
    const float* b_off = (const float*)d_in[2];
    const float* wgt   = (const float*)d_in[3];
    const float* bias  = (const float*)d_in[4];
    const float* gamma = (const float*)d_in[5];
    const float* beta  = (const float*)d_in[6];
    const float* rmean = (const float*)d_in[7];
    const float* rvar  = (const float*)d_in[8];
    float* outp = (float*)d_out;

    // 4*128*128 pixels / 64 per block = 1024 blocks
    DeformConv_14568529068723_kernel<<<dim3(1024), dim3(256), 0, stream>>>(
        x, w_off, b_off, wgt, bias, gamma, beta, rmean, rvar, outp);
}

// Round 8
// 223.137 us; speedup vs baseline: 3.9794x; 2.8042x over previous
//
#include <hip/hip_runtime.h>
#include <hip/hip_bf16.h>

// DCN v2 (modulated deformable 3x3 conv) + BN(eval) + ReLU, fused, MFMA version.
// B=4, C=64, O=64, H=W=128. fp32 in/out; bf16 MFMA (16x16x32) w/ fp32 accum.
//
// Both convs are GEMMs per 64-pixel block:
//   offset conv: [64px x 576] x [576 x 27->32]
//   main conv  : [64px x 576] x [576 x 64]   (A = deformable-sampled values)
// K layout: k = c*10 + tap (taps padded 9->10 with zeros) -> K=640, chunked 2x320.
// A staged in LDS bf16 [px][Kpad=328]; B pre-swizzled into d_ws (prep kernel)
// in fragment order: Wb[kb][nt][lane][j] = W[k=kb*32+(lane>>4)*8+j][n=nt*16+(lane&15)].
//
// MFMA layouts (m89/m120-verified): A[m=lane&15][k=(lane>>4)*8+j];
// B[k=(lane>>4)*8+j][n=lane&15]; D: n=lane&15, m=(lane>>4)*4+reg.
//
// REGISTER NOTE (R4-R7 evidence): plain __launch_bounds__(256) only; any
// min-waves arg triggers catastrophic scratch spill.

#define HH 128
#define WW 128
#define KPAD 328            // 320 + 8 pad: row stride 164 dwords -> 2-way (free) LDS reads

typedef __attribute__((ext_vector_type(8))) short bf16x8;
typedef __attribute__((ext_vector_type(4))) float f32x4;

__device__ __forceinline__ unsigned short f2bf(float f) {
    union { __hip_bfloat16 b; unsigned short u; } cv;
    cv.b = __float2bfloat16(f);
    return cv.u;
}

// ws layout (ushort): WbM[20][4][64][8] = 40960 | WbO[20][2][64][8] = 20480
#define WBM_ELEMS 40960
#define WBO_ELEMS 20480

// ---------------- prep: swizzle weights into B-fragment order, bf16 ----------------
__global__ __launch_bounds__(256) void prep_kernel(
    const float* __restrict__ w_off,
    const float* __restrict__ wgt,
    unsigned short* __restrict__ ws)
{
    int t = blockIdx.x * 256 + threadIdx.x;
    if (t < WBM_ELEMS) {
        int j = t & 7, lane = (t >> 3) & 63, nt = (t >> 9) & 3, kb = t >> 11;
        int k = kb * 32 + ((lane >> 4) << 3) + j;
        int n = nt * 16 + (lane & 15);
        int c = k / 10, tp = k - c * 10;
        ws[t] = (tp < 9) ? f2bf(wgt[n * 576 + c * 9 + tp]) : (unsigned short)0;
    } else if (t < WBM_ELEMS + WBO_ELEMS) {
        int t2 = t - WBM_ELEMS;
        int j = t2 & 7, lane = (t2 >> 3) & 63, nt = (t2 >> 9) & 1, kb = t2 >> 10;
        int k = kb * 32 + ((lane >> 4) << 3) + j;
        int n = nt * 16 + (lane & 15);
        int c = k / 10, tp = k - c * 10;
        ws[t] = (tp < 9 && n < 27) ? f2bf(w_off[n * 576 + c * 9 + tp]) : (unsigned short)0;
    }
}

// ---------------- main kernel ----------------
__global__ __launch_bounds__(256) void DeformConv_14568529068723_kernel(
    const float* __restrict__ x,
    const float* __restrict__ b_off,
    const float* __restrict__ bias,
    const float* __restrict__ gamma,
    const float* __restrict__ beta,
    const float* __restrict__ rmean,
    const float* __restrict__ rvar,
    const unsigned short* __restrict__ ws,
    float* __restrict__ out)
{
    __shared__ __align__(16) unsigned short samp[64 * KPAD];  // 41984 B; reused as dT f32[64][65]
    __shared__ float offs[27 * 64];                           // [oc][px]
    __shared__ float sbuf[176];                               // 0-63 scale, 64-127 bias2, 128-154 b_off

    const int tid  = threadIdx.x;
    const int lane = tid & 63;
    const int wv   = tid >> 6;

    if (tid < 64) {
        float sc = gamma[tid] * __frsqrt_rn(rvar[tid] + 1e-5f);
        sbuf[tid] = sc;
        sbuf[64 + tid] = (bias[tid] - rmean[tid]) * sc + beta[tid];
    }
    if (tid < 27) sbuf[128 + tid] = b_off[tid];

    const int p0   = blockIdx.x * 64;
    const int b    = p0 >> 14;
    const int rem0 = p0 & 16383;
    const int h    = rem0 >> 7;
    const int w    = (rem0 & 127) + lane;      // lane = pixel
    const float* xb = x + ((size_t)b << 20);

    const bf16x8* WbM = (const bf16x8*)ws;
    const bf16x8* WbO = (const bf16x8*)(ws + WBM_ELEMS);

    __syncthreads();

    // ================= offset conv via MFMA =================
    f32x4 accO0 = {0.f, 0.f, 0.f, 0.f};
    f32x4 accO1 = {0.f, 0.f, 0.f, 0.f};
    for (int cc = 0; cc < 2; ++cc) {
        // stage regular 3x3 patches for channels [cc*32 + 8*wv, +8)
#pragma unroll
        for (int ci = 0; ci < 8; ++ci) {
            int c = cc * 32 + 8 * wv + ci;
            const float* xc = xb + (c << 14);
            float v[10];
            v[9] = 0.f;
#pragma unroll
            for (int t = 0; t < 9; ++t) {
                int yy = h + t / 3 - 1;
                int xx = w + t % 3 - 1;
                bool ok = (yy >= 0) & (yy < HH) & (xx >= 0) & (xx < WW);
                int yc = min(max(yy, 0), HH - 1);
                int xcl = min(max(xx, 0), WW - 1);
                float val = xc[yc * WW + xcl];
                v[t] = ok ? val : 0.f;
            }
            unsigned int* dst = (unsigned int*)&samp[lane * KPAD + (8 * wv + ci) * 10];
#pragma unroll
            for (int tp = 0; tp < 5; ++tp)
                dst[tp] = (unsigned int)f2bf(v[2 * tp]) | ((unsigned int)f2bf(v[2 * tp + 1]) << 16);
        }
        __syncthreads();
#pragma unroll
        for (int st = 0; st < 10; ++st) {
            bf16x8 af = *(const bf16x8*)&samp[(16 * wv + (lane & 15)) * KPAD + st * 32 + ((lane >> 4) << 3)];
            int kb = cc * 10 + st;
            bf16x8 b0 = WbO[(kb * 2 + 0) * 64 + lane];
            bf16x8 b1 = WbO[(kb * 2 + 1) * 64 + lane];
            accO0 = __builtin_amdgcn_mfma_f32_16x16x32_bf16(af, b0, accO0, 0, 0, 0);
            accO1 = __builtin_amdgcn_mfma_f32_16x16x32_bf16(af, b1, accO1, 0, 0, 0);
        }
        __syncthreads();
    }
    // D -> offs[oc][px], + bias, sigmoid masks. n=lane&15, m=(lane>>4)*4+r (+16*wv)
    {
        int n0 = lane & 15;
        int mB = 16 * wv + ((lane >> 4) << 2);
#pragma unroll
        for (int r = 0; r < 4; ++r) {
            offs[n0 * 64 + mB + r] = accO0[r] + sbuf[128 + n0];          // oc 0..15: never sigmoid
            int n1 = 16 + n0;
            if (n1 < 27) {
                float vv = accO1[r] + sbuf[128 + n1];
                if (n1 >= 18) vv = 1.0f / (1.0f + __expf(-vv));
                offs[n1 * 64 + mB + r] = vv;
            }
        }
    }
    __syncthreads();

    // ================= bilinear setup (per-lane) =================
    int   ofs4[9][4];
    float cw[9][4];
#pragma unroll
    for (int k = 0; k < 9; ++k) {
        float o1 = offs[(2 * k) * 64 + lane];
        float o2 = offs[(2 * k + 1) * 64 + lane];
        float m  = offs[(18 + k) * 64 + lane];
        float py = (float)(h + k / 3 - 1) + o1;
        float px = (float)(w + k % 3 - 1) + o2;
        float y0f = floorf(py), x0f = floorf(px);
        float dy = py - y0f, dx = px - x0f;
        int y0 = (int)y0f, x0 = (int)x0f;
        int y1 = y0 + 1, x1 = x0 + 1;
        int yc0 = min(max(y0, 0), HH - 1), yc1 = min(max(y1, 0), HH - 1);
        int xc0 = min(max(x0, 0), WW - 1), xc1 = min(max(x1, 0), WW - 1);
        float vy0 = (y0 >= 0 && y0 < HH) ? 1.0f : 0.0f;
        float vy1 = (y1 >= 0 && y1 < HH) ? 1.0f : 0.0f;
        float vx0 = (x0 >= 0 && x0 < WW) ? 1.0f : 0.0f;
        float vx1 = (x1 >= 0 && x1 < WW) ? 1.0f : 0.0f;
        ofs4[k][0] = yc0 * WW + xc0;
        ofs4[k][1] = yc0 * WW + xc1;
        ofs4[k][2] = yc1 * WW + xc0;
        ofs4[k][3] = yc1 * WW + xc1;
        cw[k][0] = (1.0f - dy) * (1.0f - dx) * m * vy0 * vx0;
        cw[k][1] = (1.0f - dy) * dx * m * vy0 * vx1;
        cw[k][2] = dy * (1.0f - dx) * m * vy1 * vx0;
        cw[k][3] = dy * dx * m * vy1 * vx1;
    }

    // ================= main conv via MFMA =================
    f32x4 acc[4];
#pragma unroll
    for (int nt = 0; nt < 4; ++nt) acc[nt] = (f32x4){0.f, 0.f, 0.f, 0.f};

    for (int cc = 0; cc < 2; ++cc) {
#pragma unroll
        for (int ci = 0; ci < 8; ++ci) {
            int c = cc * 32 + 8 * wv + ci;
            const float* xc = xb + (c << 14);
            float sv[10];
            sv[9] = 0.f;
#pragma unroll
            for (int k = 0; k < 9; ++k) {
                sv[k] = cw[k][0] * xc[ofs4[k][0]] + cw[k][1] * xc[ofs4[k][1]]
                      + cw[k][2] * xc[ofs4[k][2]] + cw[k][3] * xc[ofs4[k][3]];
            }
            unsigned int* dst = (unsigned int*)&samp[lane * KPAD + (8 * wv + ci) * 10];
#pragma unroll
            for (int tp = 0; tp < 5; ++tp)
                dst[tp] = (unsigned int)f2bf(sv[2 * tp]) | ((unsigned int)f2bf(sv[2 * tp + 1]) << 16);
        }
        __syncthreads();
#pragma unroll
        for (int st = 0; st < 10; ++st) {
            bf16x8 af = *(const bf16x8*)&samp[(16 * wv + (lane & 15)) * KPAD + st * 32 + ((lane >> 4) << 3)];
            int kb = cc * 10 + st;
#pragma unroll
            for (int nt = 0; nt < 4; ++nt) {
                bf16x8 bf = WbM[(kb * 4 + nt) * 64 + lane];
                acc[nt] = __builtin_amdgcn_mfma_f32_16x16x32_bf16(af, bf, acc[nt], 0, 0, 0);
            }
        }
        __syncthreads();
    }

    // ================= epilogue: transpose via LDS, BN + ReLU, coalesced stores ==========
    float* dT = (float*)samp;   // [64 o][65]
    {
        int n0 = lane & 15;
        int mB = 16 * wv + ((lane >> 4) << 2);
#pragma unroll
        for (int nt = 0; nt < 4; ++nt)
#pragma unroll
            for (int r = 0; r < 4; ++r)
                dT[(nt * 16 + n0) * 65 + mB + r] = acc[nt][r];
    }
    __syncthreads();
#pragma unroll
    for (int i = 0; i < 16; ++i) {
        int o = 16 * wv + i;
        float v = dT[o * 65 + lane];
        v = fmaxf(fmaf(v, sbuf[o], sbuf[64 + o]), 0.0f);
        out[(((size_t)(b * 64 + o)) << 14) + rem0 + lane] = v;
    }
}

extern "C" void kernel_launch(void* const* d_in, const int* in_sizes, int n_in,
                              void* d_out, int out_size, void* d_ws, size_t ws_size,
                              hipStream_t stream) {
    (void)in_sizes; (void)n_in; (void)ws_size; (void)out_size;
    const float* x     = (const float*)d_in[0];
    const float* w_off = (const float*)d_in[1];
    const float* b_off = (const float*)d_in[2];
    const float* wgt   = (const float*)d_in[3];
    const float* bias  = (const float*)d_in[4];
    const float* gamma = (const float*)d_in[5];
    const float* beta  = (const float*)d_in[6];
    const float* rmean = (const float*)d_in[7];
    const float* rvar  = (const float*)d_in[8];
    unsigned short* wsB = (unsigned short*)d_ws;
    float* outp = (float*)d_out;

    prep_kernel<<<dim3(240), dim3(256), 0, stream>>>(w_off, wgt, wsB);
    DeformConv_14568529068723_kernel<<<dim3(1024), dim3(256), 0, stream>>>(
        x, b_off, bias, gamma, beta, rmean, rvar, wsB, outp);
}